// Round 4
// baseline (197.445 us; speedup 1.0000x reference)
//
#include <hip/hip_runtime.h>
#include <hip/hip_bf16.h>
#include <math.h>

// Problem constants (B=32, S=512, H=768)
#define Hh   768
#define Ss   512
#define Bb   32
#define NTOK (Bb * Ss)          // 16384
#define NTOT (NTOK * Hh)        // 12582912

// ---------------- Threefry-2x32, key = (0, 42)  (jax.random.key(42)) --------
// Core verified against Random123 known-answer: key(0,0),ctr(0,0) ->
// 0x6b200159, 0x99ba4efe.
__device__ __forceinline__ void tfr(unsigned &x0, unsigned &x1, int r) {
  x0 += x1;
  x1 = (x1 << r) | (x1 >> (32 - r));
  x1 ^= x0;
}

__device__ __forceinline__ uint2 threefry_0_42(unsigned x0, unsigned x1) {
  const unsigned ks0 = 0u, ks1 = 42u, ks2 = 0x1BD11BF0u; // 0^42^0x1BD11BDA
  x0 += ks0; x1 += ks1;
  tfr(x0, x1, 13); tfr(x0, x1, 15); tfr(x0, x1, 26); tfr(x0, x1, 6);
  x0 += ks1; x1 += ks2 + 1u;
  tfr(x0, x1, 17); tfr(x0, x1, 29); tfr(x0, x1, 16); tfr(x0, x1, 24);
  x0 += ks2; x1 += ks0 + 2u;
  tfr(x0, x1, 13); tfr(x0, x1, 15); tfr(x0, x1, 26); tfr(x0, x1, 6);
  x0 += ks0; x1 += ks1 + 3u;
  tfr(x0, x1, 17); tfr(x0, x1, 29); tfr(x0, x1, 16); tfr(x0, x1, 24);
  x0 += ks1; x1 += ks2 + 4u;
  tfr(x0, x1, 13); tfr(x0, x1, 15); tfr(x0, x1, 26); tfr(x0, x1, 6);
  x0 += ks2; x1 += ks0 + 5u;
  return make_uint2(x0, x1);
}

// XLA ErfInv32 (Giles polynomial), w = -log1p(-x*x)
__device__ __forceinline__ float erfinv_xla(float x) {
  float w = -log1pf(-x * x);
  float p;
  if (w < 5.0f) {
    w = w - 2.5f;
    p = 2.81022636e-08f;
    p = fmaf(p, w, 3.43273939e-07f);
    p = fmaf(p, w, -3.5233877e-06f);
    p = fmaf(p, w, -4.39150654e-06f);
    p = fmaf(p, w, 0.00021858087f);
    p = fmaf(p, w, -0.00125372503f);
    p = fmaf(p, w, -0.00417768164f);
    p = fmaf(p, w, 0.246640727f);
    p = fmaf(p, w, 1.50140941f);
  } else {
    w = sqrtf(w) - 3.0f;
    p = -0.000200214257f;
    p = fmaf(p, w, 0.000100950558f);
    p = fmaf(p, w, 0.00134934322f);
    p = fmaf(p, w, -0.00367342844f);
    p = fmaf(p, w, 0.00573950773f);
    p = fmaf(p, w, -0.0076224613f);
    p = fmaf(p, w, 0.00943887047f);
    p = fmaf(p, w, 1.00167406f);
    p = fmaf(p, w, 2.83297682f);
  }
  return p * x;
}

// noise = jax.random.normal(key(42), [NTOT])[i] * 0.5
// JAX >= 0.4.30: threefry_partitionable default ON ->
//   ctr = (hi32(i), lo32(i)) = (0, i); 32-bit output = bits1 ^ bits2.
__device__ __forceinline__ float noise_at(unsigned i) {
  uint2 r = threefry_0_42(0u, i);
  unsigned bits = r.x ^ r.y;
  float f = __uint_as_float((bits >> 9) | 0x3F800000u) - 1.0f; // [0,1)
  const float LO = -0.99999994f;                    // nextafter(-1,0) in f32
  float u = fmaxf(LO, f * 2.0f + LO);               // (maxval-minval)==2.0f exactly
  return 1.41421354f * erfinv_xla(u) * 0.5f;        // sqrt(2)*erfinv(u)*STD
}

// ---------------- Kernel 1: per-row stats of importance_scores --------------
// ws layout: [0..31]=rowmax, [32..63]=rowmin(inf->99), [64..95]=rowsum
__global__ __launch_bounds__(512) void row_stats_kernel(
    const float* __restrict__ imp, float* __restrict__ ws) {
  int b = blockIdx.x;
  int tid = threadIdx.x;
  float v = imp[b * Ss + tid];
  float vmax = v;
  float vmin = isinf(v) ? 99.0f : v;
  float vsum = v;
  for (int o = 32; o > 0; o >>= 1) {
    vmax = fmaxf(vmax, __shfl_down(vmax, o));
    vmin = fminf(vmin, __shfl_down(vmin, o));
    vsum += __shfl_down(vsum, o);
  }
  __shared__ float smax[8], smin[8], ssum[8];
  int wave = tid >> 6, lane = tid & 63;
  if (lane == 0) { smax[wave] = vmax; smin[wave] = vmin; ssum[wave] = vsum; }
  __syncthreads();
  if (tid == 0) {
    float a = smax[0], m = smin[0], c = ssum[0];
    for (int w = 1; w < 8; ++w) {
      a = fmaxf(a, smax[w]); m = fminf(m, smin[w]); c += ssum[w];
    }
    ws[b] = a; ws[32 + b] = m; ws[64 + b] = c;
  }
}

// ---------------- Kernel 2: fused embed + LN + noise, f32 output ------------
__global__ __launch_bounds__(256) void bert_embed_ln_noise_kernel(
    const int* __restrict__ ids, const int* __restrict__ tts,
    const float* __restrict__ imp,
    const float* __restrict__ wemb, const float* __restrict__ pemb,
    const float* __restrict__ temb, const float* __restrict__ gamma,
    const float* __restrict__ beta, const float* __restrict__ stats,
    float* __restrict__ out) {
  const int t = blockIdx.x;            // token index in [0, 16384)
  const int b = t >> 9;
  const int s = t & 511;
  const int tid = threadIdx.x;

  const int id = ids[t];
  const int tt = tts[t];
  const float* wr = wemb + (size_t)id * Hh;
  const float* pr = pemb + (size_t)s * Hh;
  const float* tr = temb + (size_t)tt * Hh;

  float e0 = wr[tid]       + pr[tid]       + tr[tid];
  float e1 = wr[tid + 256] + pr[tid + 256] + tr[tid + 256];
  float e2 = wr[tid + 512] + pr[tid + 512] + tr[tid + 512];

  __shared__ float red[4];
  __shared__ float sh_sigma;
  const int wave = tid >> 6, lane = tid & 63;

  // mean
  float ps = e0 + e1 + e2;
  for (int o = 32; o > 0; o >>= 1) ps += __shfl_down(ps, o);
  if (lane == 0) red[wave] = ps;
  __syncthreads();
  const float mu = (red[0] + red[1] + red[2] + red[3]) * (1.0f / Hh);
  __syncthreads();

  // variance
  const float d0 = e0 - mu, d1 = e1 - mu, d2 = e2 - mu;
  float pv = d0 * d0 + d1 * d1 + d2 * d2;
  for (int o = 32; o > 0; o >>= 1) pv += __shfl_down(pv, o);
  if (lane == 0) red[wave] = pv;

  // sigma for this token (scalar) — computed while var reduction settles
  if (tid == 0) {
    float total = 0.0f;
    for (int w = 0; w < 32; ++w) total += stats[64 + w];
    const float score = imp[t];
    float sig = 0.0f;
    if (s != 0) {
      const bool fin = isfinite(score);
      const float mx = stats[b], mn = stats[32 + b];
      const float val = (total == 0.0f) ? score : (score - mn) / (mx - mn);
      const float sc = fin ? val : 0.0f;
      sig = fin ? (1.0f - sc) : 0.0f;
    }
    sh_sigma = sig;
  }
  __syncthreads();
  const float var = (red[0] + red[1] + red[2] + red[3]) * (1.0f / Hh);
  const float rstd = rsqrtf(var + 1e-12f);
  const float sig = sh_sigma;

  const float y0 = d0 * rstd * gamma[tid]       + beta[tid];
  const float y1 = d1 * rstd * gamma[tid + 256] + beta[tid + 256];
  const float y2 = d2 * rstd * gamma[tid + 512] + beta[tid + 512];

  const unsigned base = (unsigned)t * Hh;
  const float n0 = noise_at(base + tid);
  const float n1 = noise_at(base + tid + 256);
  const float n2 = noise_at(base + tid + 512);

  out[base + tid]       = fmaf(n0 * sig, y0, y0);
  out[base + tid + 256] = fmaf(n1 * sig, y1, y1);
  out[base + tid + 512] = fmaf(n2 * sig, y2, y2);
}

extern "C" void kernel_launch(void* const* d_in, const int* in_sizes, int n_in,
                              void* d_out, int out_size, void* d_ws, size_t ws_size,
                              hipStream_t stream) {
  const int*   ids   = (const int*)d_in[0];
  const int*   tts   = (const int*)d_in[1];
  const float* imp   = (const float*)d_in[2];
  const float* wemb  = (const float*)d_in[3];
  const float* pemb  = (const float*)d_in[4];
  const float* temb  = (const float*)d_in[5];
  const float* gamma = (const float*)d_in[6];
  const float* beta  = (const float*)d_in[7];
  float* out   = (float*)d_out;
  float* stats = (float*)d_ws;

  row_stats_kernel<<<Bb, Ss, 0, stream>>>(imp, stats);
  bert_embed_ln_noise_kernel<<<NTOK, 256, 0, stream>>>(
      ids, tts, imp, wemb, pemb, temb, gamma, beta, stats, out);
}

// Round 5
// 173.589 us; speedup vs baseline: 1.1374x; 1.1374x over previous
//
#include <hip/hip_runtime.h>
#include <math.h>

// Problem constants (B=32, S=512, H=768)
#define Hh   768
#define Ss   512
#define Bb   32
#define NTOK (Bb * Ss)          // 16384
#define NT   192                // threads/block; 4 floats each = 768

// ---------------- Threefry-2x32, key = (0, 42), partitionable fold ----------
// ctr = (0, i); output = x0 ^ x1. Core verified vs Random123 known-answer.
__device__ __forceinline__ void tfr(unsigned &x0, unsigned &x1, int r) {
  x0 += x1;
  x1 = (x1 << r) | (x1 >> (32 - r));
  x1 ^= x0;
}

__device__ __forceinline__ unsigned tf_bits_0_42(unsigned ctr) {
  const unsigned ks1 = 42u, ks2 = 0x1BD11BF0u; // 0^42^0x1BD11BDA
  unsigned x0 = 0u, x1 = ctr + ks1;
  tfr(x0,x1,13); tfr(x0,x1,15); tfr(x0,x1,26); tfr(x0,x1,6);
  x0 += ks1; x1 += ks2 + 1u;
  tfr(x0,x1,17); tfr(x0,x1,29); tfr(x0,x1,16); tfr(x0,x1,24);
  x0 += ks2; x1 += 2u;
  tfr(x0,x1,13); tfr(x0,x1,15); tfr(x0,x1,26); tfr(x0,x1,6);
  x1 += ks1 + 3u;
  tfr(x0,x1,17); tfr(x0,x1,29); tfr(x0,x1,16); tfr(x0,x1,24);
  x0 += ks1; x1 += ks2 + 4u;
  tfr(x0,x1,13); tfr(x0,x1,15); tfr(x0,x1,26); tfr(x0,x1,6);
  x0 += ks2; x1 += 5u;
  return x0 ^ x1;
}

// bits -> u in [-0.99999994, 1) -> erfinv(u)  (Giles poly, native log)
__device__ __forceinline__ float erfinv_bits(unsigned bits) {
  float f = __uint_as_float((bits >> 9) | 0x3F800000u) - 1.0f; // [0,1)
  const float LO = -0.99999994f;
  float x = fmaxf(LO, fmaf(f, 2.0f, LO));
  // w = -log1p(-x^2); fmaf avoids cancellation, native log is ~1 ulp
  float w = -__logf(fmaf(-x, x, 1.0f));
  float p;
  if (w < 5.0f) {
    w -= 2.5f;
    p = 2.81022636e-08f;
    p = fmaf(p, w, 3.43273939e-07f);
    p = fmaf(p, w, -3.5233877e-06f);
    p = fmaf(p, w, -4.39150654e-06f);
    p = fmaf(p, w, 0.00021858087f);
    p = fmaf(p, w, -0.00125372503f);
    p = fmaf(p, w, -0.00417768164f);
    p = fmaf(p, w, 0.246640727f);
    p = fmaf(p, w, 1.50140941f);
  } else {
    w = sqrtf(w) - 3.0f;
    p = -0.000200214257f;
    p = fmaf(p, w, 0.000100950558f);
    p = fmaf(p, w, 0.00134934322f);
    p = fmaf(p, w, -0.00367342844f);
    p = fmaf(p, w, 0.00573950773f);
    p = fmaf(p, w, -0.0076224613f);
    p = fmaf(p, w, 0.00943887047f);
    p = fmaf(p, w, 1.00167406f);
    p = fmaf(p, w, 2.83297682f);
  }
  return p * x;
}

// ---------------- Kernel 1: per-row stats of importance_scores --------------
// ws layout: [0..31]=rowmax, [32..63]=rowmin(inf->99), [64..95]=rowsum
__global__ __launch_bounds__(512) void row_stats_kernel(
    const float* __restrict__ imp, float* __restrict__ ws) {
  int b = blockIdx.x;
  int tid = threadIdx.x;
  float v = imp[b * Ss + tid];
  float vmax = v;
  float vmin = isinf(v) ? 99.0f : v;
  float vsum = v;
  for (int o = 32; o > 0; o >>= 1) {
    vmax = fmaxf(vmax, __shfl_down(vmax, o));
    vmin = fminf(vmin, __shfl_down(vmin, o));
    vsum += __shfl_down(vsum, o);
  }
  __shared__ float smax[8], smin[8], ssum[8];
  int wave = tid >> 6, lane = tid & 63;
  if (lane == 0) { smax[wave] = vmax; smin[wave] = vmin; ssum[wave] = vsum; }
  __syncthreads();
  if (tid == 0) {
    float a = smax[0], m = smin[0], c = ssum[0];
    for (int w = 1; w < 8; ++w) {
      a = fmaxf(a, smax[w]); m = fminf(m, smin[w]); c += ssum[w];
    }
    ws[b] = a; ws[32 + b] = m; ws[64 + b] = c;
  }
}

// ---------------- Kernel 2: fused embed + LN + noise, float4 ----------------
__global__ __launch_bounds__(NT) void bert_embed_ln_noise_kernel(
    const int* __restrict__ ids, const int* __restrict__ tts,
    const float* __restrict__ imp,
    const float* __restrict__ wemb, const float* __restrict__ pemb,
    const float* __restrict__ temb, const float* __restrict__ gamma,
    const float* __restrict__ beta, const float* __restrict__ stats,
    float* __restrict__ out) {
  const int t = blockIdx.x;            // token index in [0, 16384)
  const int b = t >> 9;
  const int s = t & 511;
  const int tid = threadIdx.x;

  const int id = ids[t];
  const int tt = tts[t];
  const float4 wv = ((const float4*)(wemb + (size_t)id * Hh))[tid];
  const float4 pv = ((const float4*)(pemb + (size_t)s  * Hh))[tid];
  const float4 tv = ((const float4*)(temb + (size_t)tt * Hh))[tid];

  const float e0 = wv.x + pv.x + tv.x;
  const float e1 = wv.y + pv.y + tv.y;
  const float e2 = wv.z + pv.z + tv.z;
  const float e3 = wv.w + pv.w + tv.w;

  // noise bits: independent of the reductions -> compute early for ILP
  const unsigned base = (unsigned)t * Hh + 4u * (unsigned)tid;
  const unsigned r0 = tf_bits_0_42(base);
  const unsigned r1 = tf_bits_0_42(base + 1u);
  const unsigned r2 = tf_bits_0_42(base + 2u);
  const unsigned r3 = tf_bits_0_42(base + 3u);
  const float v0 = erfinv_bits(r0);
  const float v1 = erfinv_bits(r1);
  const float v2 = erfinv_bits(r2);
  const float v3 = erfinv_bits(r3);

  __shared__ float redm[3], redv[3];
  __shared__ float sh_ssc;
  const int wave = tid >> 6, lane = tid & 63;

  // mean
  float ps = (e0 + e1) + (e2 + e3);
  #pragma unroll
  for (int o = 1; o < 64; o <<= 1) ps += __shfl_xor(ps, o);
  if (lane == 0) redm[wave] = ps;
  __syncthreads();
  const float mu = (redm[0] + redm[1] + redm[2]) * (1.0f / Hh);

  // variance
  const float d0 = e0 - mu, d1 = e1 - mu, d2 = e2 - mu, d3 = e3 - mu;
  float pvv = (d0 * d0 + d1 * d1) + (d2 * d2 + d3 * d3);
  #pragma unroll
  for (int o = 1; o < 64; o <<= 1) pvv += __shfl_xor(pvv, o);
  if (lane == 0) redv[wave] = pvv;

  // per-token sigma * (sqrt2*STD), computed while var reduction settles
  if (tid == 0) {
    float total = 0.0f;
    for (int w = 0; w < 32; ++w) total += stats[64 + w];
    const float score = imp[t];
    float sig = 0.0f;
    if (s != 0) {
      const bool fin = isfinite(score);
      const float mx = stats[b], mn = stats[32 + b];
      const float val = (total == 0.0f) ? score : (score - mn) / (mx - mn);
      sig = fin ? (1.0f - val) : 0.0f;
    }
    sh_ssc = sig * 0.70710677f;   // sqrt(2) * STD(=0.5) folded
  }
  __syncthreads();
  const float var = (redv[0] + redv[1] + redv[2]) * (1.0f / Hh);
  const float rstd = rsqrtf(var + 1e-12f);
  const float ssc = sh_ssc;

  const float4 g4 = ((const float4*)gamma)[tid];
  const float4 b4 = ((const float4*)beta)[tid];
  const float y0 = fmaf(d0 * rstd, g4.x, b4.x);
  const float y1 = fmaf(d1 * rstd, g4.y, b4.y);
  const float y2 = fmaf(d2 * rstd, g4.z, b4.z);
  const float y3 = fmaf(d3 * rstd, g4.w, b4.w);

  float4 o4;
  o4.x = fmaf(v0 * ssc, y0, y0);
  o4.y = fmaf(v1 * ssc, y1, y1);
  o4.z = fmaf(v2 * ssc, y2, y2);
  o4.w = fmaf(v3 * ssc, y3, y3);
  ((float4*)(out + (size_t)t * Hh))[tid] = o4;
}

extern "C" void kernel_launch(void* const* d_in, const int* in_sizes, int n_in,
                              void* d_out, int out_size, void* d_ws, size_t ws_size,
                              hipStream_t stream) {
  const int*   ids   = (const int*)d_in[0];
  const int*   tts   = (const int*)d_in[1];
  const float* imp   = (const float*)d_in[2];
  const float* wemb  = (const float*)d_in[3];
  const float* pemb  = (const float*)d_in[4];
  const float* temb  = (const float*)d_in[5];
  const float* gamma = (const float*)d_in[6];
  const float* beta  = (const float*)d_in[7];
  float* out   = (float*)d_out;
  float* stats = (float*)d_ws;

  row_stats_kernel<<<Bb, Ss, 0, stream>>>(imp, stats);
  bert_embed_ln_noise_kernel<<<NTOK, NT, 0, stream>>>(
      ids, tts, imp, wemb, pemb, temb, gamma, beta, stats, out);
}